// Round 2
// baseline (542.466 us; speedup 1.0000x reference)
//
#include <hip/hip_runtime.h>
#include <hip/hip_bf16.h>

#define NN 2560        // nodes
#define NE 163840      // edges
#define NH 4           // heads
#define NC 128         // channels per head
#define NF 512         // NH*NC
#define OUTE 40

typedef short bf16x8 __attribute__((ext_vector_type(8)));
typedef float f32x4 __attribute__((ext_vector_type(4)));

__device__ inline ushort f2bf(float f) {
    uint u = __float_as_uint(f);
    uint r = u + 0x7FFF + ((u >> 16) & 1);   // round-to-nearest-even
    return (ushort)(r >> 16);
}

// ---------------- kernel 1: edge weights + degree count -------------------
__global__ void k_edge_init(const int* __restrict__ ei, const float* __restrict__ pos,
                            float* __restrict__ ew, int* __restrict__ deg) {
    int e = blockIdx.x * 256 + threadIdx.x;
    if (e >= NE) return;
    int s = ei[e], d = ei[NE + e];
    float dx = pos[2 * s] - pos[2 * d];
    float dy = pos[2 * s + 1] - pos[2 * d + 1];
    ew[e] = 1.0f / (sqrtf(dx * dx + dy * dy) + 1e-6f);
    atomicAdd(&deg[d], 1);
}

// ---------------- kernel 2: exclusive scan of deg -> offs (single block) ---
__global__ void k_scan(const int* __restrict__ deg, int* __restrict__ offs) {
    __shared__ int cs[256];
    int t = threadIdx.x;
    int base = t * 10;
    int local[10];
    int s = 0;
#pragma unroll
    for (int i = 0; i < 10; i++) { local[i] = deg[base + i]; s += local[i]; }
    cs[t] = s;
    __syncthreads();
    for (int off = 1; off < 256; off <<= 1) {
        int v = (t >= off) ? cs[t - off] : 0;
        __syncthreads();
        cs[t] += v;
        __syncthreads();
    }
    int excl = (t == 0) ? 0 : cs[t - 1];
#pragma unroll
    for (int i = 0; i < 10; i++) { offs[base + i] = excl; excl += local[i]; }
    if (t == 255) offs[NN] = excl;
}

// ---------------- kernel 3: CSR fill (edge id + src id) -------------------
__global__ void k_csr_fill(const int* __restrict__ ei, const int* __restrict__ offs,
                           int* __restrict__ cursor, int* __restrict__ csr,
                           int* __restrict__ csr_src) {
    int e = blockIdx.x * 256 + threadIdx.x;
    if (e >= NE) return;
    int s = ei[e], d = ei[NE + e];
    int p = atomicAdd(&cursor[d], 1);
    csr[offs[d] + p] = e;
    csr_src[offs[d] + p] = s;
}

// ---------------- kernel 4: per-head edge-attention scalars, both layers --
__global__ void k_dote2(const float* __restrict__ We1, const float* __restrict__ ae1,
                        const float* __restrict__ We2, const float* __restrict__ ae2,
                        float* __restrict__ dote) {
    int t = threadIdx.x;
    const float* W = blockIdx.x ? We2 : We1;
    const float* A = blockIdx.x ? ae2 : ae1;
    int w = t >> 6, l = t & 63;
    float p = W[w * 128 + l] * A[w * 128 + l] + W[w * 128 + 64 + l] * A[w * 128 + 64 + l];
#pragma unroll
    for (int o = 32; o > 0; o >>= 1) p += __shfl_down(p, o);
    if (l == 0) dote[blockIdx.x * 4 + w] = p;
}

// ---------------- kernel 5: W2 transpose + bf16 cast: BT[n][k] ------------
__global__ __launch_bounds__(256) void k_w2t(const float* __restrict__ W2,
                                             ushort* __restrict__ BT) {
    __shared__ ushort tile[64][72];
    int k0 = blockIdx.y * 64, n0 = blockIdx.x * 64;
    int t = threadIdx.x;
    int r = t >> 2, cseg = (t & 3) * 16;
#pragma unroll
    for (int c = 0; c < 16; c += 4) {
        float4 v = *(const float4*)&W2[(k0 + r) * 512 + n0 + cseg + c];
        tile[cseg + c + 0][r] = f2bf(v.x);
        tile[cseg + c + 1][r] = f2bf(v.y);
        tile[cseg + c + 2][r] = f2bf(v.z);
        tile[cseg + c + 3][r] = f2bf(v.w);
    }
    __syncthreads();
    *(uint4*)&BT[(n0 + r) * 512 + k0 + cseg]     = *(uint4*)&tile[r][cseg];
    *(uint4*)&BT[(n0 + r) * 512 + k0 + cseg + 8] = *(uint4*)&tile[r][cseg + 8];
}

// ---------------- kernel 6: GEMM1 h = x @ W1 (K=32) -----------------------
__global__ void k_gemm1(const float* __restrict__ x, const float* __restrict__ W1,
                        float* __restrict__ h) {
    int idx = blockIdx.x * 256 + threadIdx.x;   // n*512 + j
    int n = idx >> 9, j = idx & 511;
    const float* xr = x + n * 32;
    float acc = 0.f;
#pragma unroll
    for (int k = 0; k < 32; k++) acc += xr[k] * W1[k * 512 + j];
    h[idx] = acc;
}

// ---------------- kernel 7: node attention scalars a_s, a_d ---------------
// one block per node, 4 waves = 4 heads
__global__ void k_node_att(const float* __restrict__ h, const float* __restrict__ atts,
                           const float* __restrict__ attd, float* __restrict__ as_,
                           float* __restrict__ ad_) {
    int n = blockIdx.x;
    int t = threadIdx.x;
    int hd = t >> 6, l = t & 63;
    const float* hr = h + n * NF + hd * NC;
    const float* sp = atts + hd * NC;
    const float* dp = attd + hd * NC;
    float ps = hr[l] * sp[l] + hr[l + 64] * sp[l + 64];
    float pd = hr[l] * dp[l] + hr[l + 64] * dp[l + 64];
#pragma unroll
    for (int o = 32; o > 0; o >>= 1) { ps += __shfl_down(ps, o); pd += __shfl_down(pd, o); }
    if (l == 0) { as_[n * 4 + hd] = ps; ad_[n * 4 + hd] = pd; }
}

// ---------------- kernel 8: fused logits + segment softmax ---------------
// one wave per dst node; stores unnormalized exp(alpha) + per-node denom
__global__ void k_softmax2(const int* __restrict__ offs, const int* __restrict__ csr,
                           const int* __restrict__ csr_src, const float* __restrict__ ew,
                           const float4* __restrict__ as4, const float4* __restrict__ ad4,
                           const float* __restrict__ dote, float4* __restrict__ alpha4,
                           float4* __restrict__ denomv) {
    int n = blockIdx.x, l = threadIdx.x;
    int beg = offs[n], end = offs[n + 1];
    float4 ad = ad4[n];
    float d0 = dote[0], d1 = dote[1], d2 = dote[2], d3 = dote[3];
    float4 m = make_float4(-1e30f, -1e30f, -1e30f, -1e30f);
    for (int i = beg + l; i < end; i += 64) {
        int e = csr[i];
        float w = ew[e];
        float4 a = as4[csr_src[i]];
        float v;
        v = a.x + ad.x + w * d0; a.x = v > 0.f ? v : 0.2f * v;
        v = a.y + ad.y + w * d1; a.y = v > 0.f ? v : 0.2f * v;
        v = a.z + ad.z + w * d2; a.z = v > 0.f ? v : 0.2f * v;
        v = a.w + ad.w + w * d3; a.w = v > 0.f ? v : 0.2f * v;
        alpha4[e] = a;
        m.x = fmaxf(m.x, a.x); m.y = fmaxf(m.y, a.y);
        m.z = fmaxf(m.z, a.z); m.w = fmaxf(m.w, a.w);
    }
#pragma unroll
    for (int o = 32; o > 0; o >>= 1) {
        m.x = fmaxf(m.x, __shfl_xor(m.x, o)); m.y = fmaxf(m.y, __shfl_xor(m.y, o));
        m.z = fmaxf(m.z, __shfl_xor(m.z, o)); m.w = fmaxf(m.w, __shfl_xor(m.w, o));
    }
    float4 ss = make_float4(0.f, 0.f, 0.f, 0.f);
    for (int i = beg + l; i < end; i += 64) {
        int e = csr[i];
        float4 a = alpha4[e];
        a.x = __expf(a.x - m.x); a.y = __expf(a.y - m.y);
        a.z = __expf(a.z - m.z); a.w = __expf(a.w - m.w);
        alpha4[e] = a;
        ss.x += a.x; ss.y += a.y; ss.z += a.z; ss.w += a.w;
    }
#pragma unroll
    for (int o = 32; o > 0; o >>= 1) {
        ss.x += __shfl_xor(ss.x, o); ss.y += __shfl_xor(ss.y, o);
        ss.z += __shfl_xor(ss.z, o); ss.w += __shfl_xor(ss.w, o);
    }
    if (l == 0) denomv[n] = ss;
}

// ---------------- kernel 9: aggregation + denom + bias + BN stats ---------
#define AGG_CHUNK 64
__global__ __launch_bounds__(256) void k_agg(const int* __restrict__ offs,
        const int* __restrict__ csr, const int* __restrict__ csr_src,
        const float* __restrict__ alpha, const float* __restrict__ h,
        const float4* __restrict__ denomv, const float* __restrict__ bias,
        float* __restrict__ out, float* __restrict__ stats) {
    __shared__ int s_src[AGG_CHUNK];
    __shared__ float s_alpha[AGG_CHUNK][4];
    int n = blockIdx.x, t = threadIdx.x;
    int beg = offs[n], end = offs[n + 1];
    int hd = t >> 6;                    // head of channels 2t, 2t+1
    float2 acc = make_float2(0.f, 0.f);
    for (int base = beg; base < end; base += AGG_CHUNK) {
        int cnt = min(AGG_CHUNK, end - base);
        __syncthreads();
        if (t < cnt) s_src[t] = csr_src[base + t];
        int ei4 = t >> 2, hh = t & 3;
        if (ei4 < cnt) s_alpha[ei4][hh] = alpha[csr[base + ei4] * 4 + hh];
        __syncthreads();
        for (int i = 0; i < cnt; i++) {
            const float2* hr = (const float2*)(h + s_src[i] * NF);
            float2 v = hr[t];
            float a = s_alpha[i][hd];
            acc.x += a * v.x; acc.y += a * v.y;
        }
    }
    float4 dn = denomv[n];
    float inv = 1.f / (((const float*)&dn)[hd] + 1e-16f);
    float o0 = acc.x * inv + bias[2 * t];
    float o1 = acc.y * inv + bias[2 * t + 1];
    *(float2*)&out[n * NF + 2 * t] = make_float2(o0, o1);
    atomicAdd(&stats[2 * t], o0);
    atomicAdd(&stats[2 * t + 1], o1);
    atomicAdd(&stats[NF + 2 * t], o0 * o0);
    atomicAdd(&stats[NF + 2 * t + 1], o1 * o1);
}

// ---------------- kernel 10a: BN apply + relu -> fp32 ---------------------
__global__ void k_bnapply_f32(const float* __restrict__ x, const float* __restrict__ stats,
                              const float* __restrict__ g, const float* __restrict__ b,
                              float* __restrict__ y) {
    int idx = blockIdx.x * 256 + threadIdx.x;
    int j = idx & 511;
    const float invn = 1.0f / (float)NN;
    float mu = stats[j] * invn;
    float var = stats[NF + j] * invn - mu * mu;
    float v = (x[idx] - mu) * rsqrtf(var + 1e-5f) * g[j] + b[j];
    y[idx] = fmaxf(v, 0.f);
}

// ---------------- kernel 10b: BN apply + relu -> bf16 ---------------------
__global__ void k_bnapply_bf16(const float* __restrict__ x, const float* __restrict__ stats,
                               const float* __restrict__ g, const float* __restrict__ b,
                               ushort* __restrict__ y) {
    int idx = blockIdx.x * 256 + threadIdx.x;
    int j = idx & 511;
    const float invn = 1.0f / (float)NN;
    float mu = stats[j] * invn;
    float var = stats[NF + j] * invn - mu * mu;
    float v = (x[idx] - mu) * rsqrtf(var + 1e-5f) * g[j] + b[j];
    y[idx] = f2bf(fmaxf(v, 0.f));
}

// ---------------- kernel 11: GEMM2 via bf16 MFMA --------------------------
// C[2560,512] = A[2560,512] @ B[512,512];  A bf16 row-major, BT bf16 [n][k]
__global__ __launch_bounds__(256) void k_gemm2_mfma(const ushort* __restrict__ A,
        const ushort* __restrict__ BT, float* __restrict__ C) {
    __shared__ ushort As[128][40];   // [m][k], +8 pad
    __shared__ ushort Bs[128][40];   // [n][k], +8 pad
    int t = threadIdx.x;
    int rowBase = blockIdx.y * 128, colBase = blockIdx.x * 128;
    int w = t >> 6, lane = t & 63;
    int wm = (w >> 1) * 64, wn = (w & 1) * 64;
    int lm = lane & 15, q = lane >> 4;
    f32x4 acc[4][4] = {};
    int sr = t >> 2, sk = (t & 3) * 8;
    for (int k0 = 0; k0 < 512; k0 += 32) {
        __syncthreads();
        uint4 a0 = *(const uint4*)&A[(rowBase + sr) * 512 + k0 + sk];
        uint4 a1 = *(const uint4*)&A[(rowBase + 64 + sr) * 512 + k0 + sk];
        uint4 b0 = *(const uint4*)&BT[(colBase + sr) * 512 + k0 + sk];
        uint4 b1 = *(const uint4*)&BT[(colBase + 64 + sr) * 512 + k0 + sk];
        *(uint4*)&As[sr][sk]      = a0;
        *(uint4*)&As[64 + sr][sk] = a1;
        *(uint4*)&Bs[sr][sk]      = b0;
        *(uint4*)&Bs[64 + sr][sk] = b1;
        __syncthreads();
        bf16x8 af[4], bf[4];
#pragma unroll
        for (int i = 0; i < 4; i++) af[i] = *(const bf16x8*)&As[wm + i * 16 + lm][q * 8];
#pragma unroll
        for (int j = 0; j < 4; j++) bf[j] = *(const bf16x8*)&Bs[wn + j * 16 + lm][q * 8];
#pragma unroll
        for (int i = 0; i < 4; i++)
#pragma unroll
            for (int j = 0; j < 4; j++)
                acc[i][j] = __builtin_amdgcn_mfma_f32_16x16x32_bf16(af[i], bf[j], acc[i][j], 0, 0, 0);
    }
#pragma unroll
    for (int i = 0; i < 4; i++) {
        int row = rowBase + wm + i * 16 + q * 4;
#pragma unroll
        for (int j = 0; j < 4; j++) {
            int col = colBase + wn + j * 16 + lm;
#pragma unroll
            for (int r = 0; r < 4; r++)
                C[(row + r) * 512 + col] = acc[i][j][r];
        }
    }
}

// ---------------- kernel 12: FC + mask + adjacency (LDS-staged) -----------
__global__ __launch_bounds__(256) void k_fc(const float* __restrict__ e2,
        const float* __restrict__ Wfc, const float* __restrict__ bfc,
        const int* __restrict__ mask, const float* __restrict__ adj,
        float* __restrict__ out) {
    __shared__ float er[8][512];
    int nb = blockIdx.x * 8, t = threadIdx.x;
#pragma unroll
    for (int i = 0; i < 4; i++) {
        int idx = t + i * 256;                       // float4 chunk id, 0..1023
        float4 v = *(const float4*)&e2[(nb + (idx >> 7)) * 512 + (idx & 127) * 4];
        *(float4*)&er[idx >> 7][(idx & 127) * 4] = v;
    }
    __syncthreads();
    for (int p = t; p < 8 * OUTE; p += 256) {
        int node = p / OUTE, j = p - node * OUTE;
        float acc = 0.f;
#pragma unroll 4
        for (int k = 0; k < 512; k++) acc += er[node][k] * Wfc[k * OUTE + j];
        int n = nb + node;
        float r = mask[n] ? (acc + bfc[j]) : 0.f;
        out[n * OUTE + j] = r + adj[n * OUTE + j];
    }
}

// ---------------- host side ----------------------------------------------
extern "C" void kernel_launch(void* const* d_in, const int* in_sizes, int n_in,
                              void* d_out, int out_size, void* d_ws, size_t ws_size,
                              hipStream_t stream) {
    const float* x       = (const float*)d_in[0];
    const int*   ei      = (const int*)d_in[1];
    const float* pos     = (const float*)d_in[2];
    const int*   mask    = (const int*)d_in[3];
    const float* adj     = (const float*)d_in[4];
    const float* W1      = (const float*)d_in[5];
    const float* atts1   = (const float*)d_in[6];
    const float* attd1   = (const float*)d_in[7];
    const float* We1     = (const float*)d_in[8];
    const float* atte1   = (const float*)d_in[9];
    const float* bias1   = (const float*)d_in[10];
    const float* g1      = (const float*)d_in[11];
    const float* be1     = (const float*)d_in[12];
    const float* W2      = (const float*)d_in[13];
    const float* atts2   = (const float*)d_in[14];
    const float* attd2   = (const float*)d_in[15];
    const float* We2     = (const float*)d_in[16];
    const float* atte2   = (const float*)d_in[17];
    const float* bias2   = (const float*)d_in[18];
    const float* g2      = (const float*)d_in[19];
    const float* be2     = (const float*)d_in[20];
    const float* Wfc     = (const float*)d_in[21];
    const float* bfc     = (const float*)d_in[22];
    float* out = (float*)d_out;

    // workspace layout (float-element offsets; every block 16B-aligned)
    char* ws = (char*)d_ws;
    int*    deg     = (int*)(ws);                       // 2560
    int*    cursor  = (int*)(ws + 2560 * 4);            // 2560
    float*  stats   = (float*)(ws + 5120 * 4);          // 2048 (layer1:1024, layer2:1024)
    // ---- zero region = first 7168 elements ----
    int*    offs    = (int*)(ws + 7168 * 4);            // 2561 (pad to 2576)
    float*  dote    = (float*)(ws + 9744 * 4);          // 8 (pad 16)
    float*  denomv  = (float*)(ws + 9760 * 4);          // 10240 (float4[2560])
    int*    csr     = (int*)(ws + 20000 * 4);           // 163840
    int*    csr_src = (int*)(ws + 183840 * 4);          // 163840
    float*  ew      = (float*)(ws + 347680 * 4);        // 163840
    float*  as_     = (float*)(ws + 511520 * 4);        // 10240
    float*  ad_     = (float*)(ws + 521760 * 4);        // 10240
    float*  alpha   = (float*)(ws + 532000 * 4);        // 655360
    float*  t0      = (float*)(ws + 1187360 * 4);       // 1310720
    float*  t1      = (float*)(ws + 2498080 * 4);       // 1310720
    ushort* t0b     = (ushort*)(ws + 3808800 * 4);      // 1310720 bf16
    ushort* W2T     = (ushort*)(ws + 4464160 * 4);      // 262144 bf16
    // total ~4.6M floats = ~18.6 MB

    hipMemsetAsync(d_ws, 0, 7168 * 4, stream);

    // graph structure + weight prep (no inter-deps except scan)
    k_edge_init<<<NE / 256, 256, 0, stream>>>(ei, pos, ew, deg);
    k_scan<<<1, 256, 0, stream>>>(deg, offs);
    k_csr_fill<<<NE / 256, 256, 0, stream>>>(ei, offs, cursor, csr, csr_src);
    k_dote2<<<2, 256, 0, stream>>>(We1, atte1, We2, atte2, dote);
    k_w2t<<<dim3(8, 8), 256, 0, stream>>>(W2, W2T);

    // ---- layer 1 ----
    k_gemm1<<<NN * NF / 256, 256, 0, stream>>>(x, W1, t0);
    k_node_att<<<NN, 256, 0, stream>>>(t0, atts1, attd1, as_, ad_);
    k_softmax2<<<NN, 64, 0, stream>>>(offs, csr, csr_src, ew, (const float4*)as_,
                                      (const float4*)ad_, dote, (float4*)alpha, (float4*)denomv);
    k_agg<<<NN, 256, 0, stream>>>(offs, csr, csr_src, alpha, t0, (const float4*)denomv,
                                  bias1, t1, stats);
    k_bnapply_bf16<<<NN * NF / 256, 256, 0, stream>>>(t1, stats, g1, be1, t0b);

    // ---- layer 2 ----
    k_gemm2_mfma<<<dim3(512 / 128, NN / 128), 256, 0, stream>>>(t0b, W2T, t0);
    k_node_att<<<NN, 256, 0, stream>>>(t0, atts2, attd2, as_, ad_);
    k_softmax2<<<NN, 64, 0, stream>>>(offs, csr, csr_src, ew, (const float4*)as_,
                                      (const float4*)ad_, dote + 4, (float4*)alpha, (float4*)denomv);
    k_agg<<<NN, 256, 0, stream>>>(offs, csr, csr_src, alpha, t0, (const float4*)denomv,
                                  bias2, t1, stats + 1024);
    k_bnapply_f32<<<NN * NF / 256, 256, 0, stream>>>(t1, stats + 1024, g2, be2, t0);

    // ---- head ----
    k_fc<<<NN / 8, 256, 0, stream>>>(t0, Wfc, bfc, mask, adj, out);
}

// Round 3
// 314.382 us; speedup vs baseline: 1.7255x; 1.7255x over previous
//
#include <hip/hip_runtime.h>
#include <hip/hip_bf16.h>

#define NN 2560        // nodes
#define NE 163840      // edges
#define NH 4           // heads
#define NC 128         // channels per head
#define NF 512         // NH*NC
#define OUTE 40

typedef short bf16x8 __attribute__((ext_vector_type(8)));
typedef float f32x4 __attribute__((ext_vector_type(4)));

__device__ inline ushort f2bf(float f) {
    uint u = __float_as_uint(f);
    uint r = u + 0x7FFF + ((u >> 16) & 1);   // round-to-nearest-even
    return (ushort)(r >> 16);
}
__device__ inline float bf2f(ushort u) {
    return __uint_as_float(((uint)u) << 16);
}

// ---------------- kernel 1: degree count ----------------------------------
__global__ void k_degcount(const int* __restrict__ ei, int* __restrict__ deg) {
    int e = blockIdx.x * 256 + threadIdx.x;
    if (e >= NE) return;
    atomicAdd(&deg[ei[NE + e]], 1);
}

// ---------------- kernel 2: exclusive scan of deg -> offs (single block) ---
__global__ void k_scan(const int* __restrict__ deg, int* __restrict__ offs) {
    __shared__ int cs[256];
    int t = threadIdx.x;
    int base = t * 10;
    int local[10];
    int s = 0;
#pragma unroll
    for (int i = 0; i < 10; i++) { local[i] = deg[base + i]; s += local[i]; }
    cs[t] = s;
    __syncthreads();
    for (int off = 1; off < 256; off <<= 1) {
        int v = (t >= off) ? cs[t - off] : 0;
        __syncthreads();
        cs[t] += v;
        __syncthreads();
    }
    int excl = (t == 0) ? 0 : cs[t - 1];
#pragma unroll
    for (int i = 0; i < 10; i++) { offs[base + i] = excl; excl += local[i]; }
    if (t == 255) offs[NN] = excl;
}

// ---------------- kernel 3: CSR fill (src id + edge weight, CSR order) ----
__global__ void k_csr_fill(const int* __restrict__ ei, const float* __restrict__ pos,
                           const int* __restrict__ offs, int* __restrict__ cursor,
                           int* __restrict__ csr_src, float* __restrict__ ew_csr) {
    int e = blockIdx.x * 256 + threadIdx.x;
    if (e >= NE) return;
    int s = ei[e], d = ei[NE + e];
    float dx = pos[2 * s] - pos[2 * d];
    float dy = pos[2 * s + 1] - pos[2 * d + 1];
    float w = 1.0f / (sqrtf(dx * dx + dy * dy) + 1e-6f);
    int p = atomicAdd(&cursor[d], 1);
    int q = offs[d] + p;
    csr_src[q] = s;
    ew_csr[q] = w;
}

// ---------------- kernel 4: per-head edge-attention scalars, both layers --
__global__ void k_dote2(const float* __restrict__ We1, const float* __restrict__ ae1,
                        const float* __restrict__ We2, const float* __restrict__ ae2,
                        float* __restrict__ dote) {
    int t = threadIdx.x;
    const float* W = blockIdx.x ? We2 : We1;
    const float* A = blockIdx.x ? ae2 : ae1;
    int w = t >> 6, l = t & 63;
    float p = W[w * 128 + l] * A[w * 128 + l] + W[w * 128 + 64 + l] * A[w * 128 + 64 + l];
#pragma unroll
    for (int o = 32; o > 0; o >>= 1) p += __shfl_down(p, o);
    if (l == 0) dote[blockIdx.x * 4 + w] = p;
}

// ---------------- kernel 5: W2 transpose + bf16 cast: BT[n][k] ------------
__global__ __launch_bounds__(256) void k_w2t(const float* __restrict__ W2,
                                             ushort* __restrict__ BT) {
    __shared__ ushort tile[64][72];
    int k0 = blockIdx.y * 64, n0 = blockIdx.x * 64;
    int t = threadIdx.x;
    int r = t >> 2, cseg = (t & 3) * 16;
#pragma unroll
    for (int c = 0; c < 16; c += 4) {
        float4 v = *(const float4*)&W2[(k0 + r) * 512 + n0 + cseg + c];
        tile[cseg + c + 0][r] = f2bf(v.x);
        tile[cseg + c + 1][r] = f2bf(v.y);
        tile[cseg + c + 2][r] = f2bf(v.z);
        tile[cseg + c + 3][r] = f2bf(v.w);
    }
    __syncthreads();
    *(uint4*)&BT[(n0 + r) * 512 + k0 + cseg]     = *(uint4*)&tile[r][cseg];
    *(uint4*)&BT[(n0 + r) * 512 + k0 + cseg + 8] = *(uint4*)&tile[r][cseg + 8];
}

// ---------------- kernel 6: GEMM1 h = x @ W1 (K=32), f32 + bf16 out -------
__global__ void k_gemm1(const float* __restrict__ x, const float* __restrict__ W1,
                        float* __restrict__ h, ushort* __restrict__ hb) {
    int idx = blockIdx.x * 256 + threadIdx.x;   // n*512 + j
    int n = idx >> 9, j = idx & 511;
    const float* xr = x + n * 32;
    float acc = 0.f;
#pragma unroll
    for (int k = 0; k < 32; k++) acc += xr[k] * W1[k * 512 + j];
    h[idx] = acc;
    hb[idx] = f2bf(acc);
}

// ---------------- kernel 7: node attention scalars a_s, a_d ---------------
// one block per node, 4 waves = 4 heads
__global__ void k_node_att(const float* __restrict__ h, const float* __restrict__ atts,
                           const float* __restrict__ attd, float* __restrict__ as_,
                           float* __restrict__ ad_) {
    int n = blockIdx.x;
    int t = threadIdx.x;
    int hd = t >> 6, l = t & 63;
    const float* hr = h + n * NF + hd * NC;
    const float* sp = atts + hd * NC;
    const float* dp = attd + hd * NC;
    float ps = hr[l] * sp[l] + hr[l + 64] * sp[l + 64];
    float pd = hr[l] * dp[l] + hr[l + 64] * dp[l + 64];
#pragma unroll
    for (int o = 32; o > 0; o >>= 1) { ps += __shfl_down(ps, o); pd += __shfl_down(pd, o); }
    if (l == 0) { as_[n * 4 + hd] = ps; ad_[n * 4 + hd] = pd; }
}

// ---------------- kernel 8: fused logits + segment softmax ---------------
// one wave per dst node; alpha stored CSR-ordered: alpha4[i] for CSR pos i
__global__ void k_softmax2(const int* __restrict__ offs, const int* __restrict__ csr_src,
                           const float* __restrict__ ew_csr,
                           const float4* __restrict__ as4, const float4* __restrict__ ad4,
                           const float* __restrict__ dote, float4* __restrict__ alpha4,
                           float4* __restrict__ denomv) {
    int n = blockIdx.x, l = threadIdx.x;
    int beg = offs[n], end = offs[n + 1];
    float4 ad = ad4[n];
    float d0 = dote[0], d1 = dote[1], d2 = dote[2], d3 = dote[3];
    float4 m = make_float4(-1e30f, -1e30f, -1e30f, -1e30f);
    for (int i = beg + l; i < end; i += 64) {
        float w = ew_csr[i];
        float4 a = as4[csr_src[i]];
        float v;
        v = a.x + ad.x + w * d0; a.x = v > 0.f ? v : 0.2f * v;
        v = a.y + ad.y + w * d1; a.y = v > 0.f ? v : 0.2f * v;
        v = a.z + ad.z + w * d2; a.z = v > 0.f ? v : 0.2f * v;
        v = a.w + ad.w + w * d3; a.w = v > 0.f ? v : 0.2f * v;
        alpha4[i] = a;
        m.x = fmaxf(m.x, a.x); m.y = fmaxf(m.y, a.y);
        m.z = fmaxf(m.z, a.z); m.w = fmaxf(m.w, a.w);
    }
#pragma unroll
    for (int o = 32; o > 0; o >>= 1) {
        m.x = fmaxf(m.x, __shfl_xor(m.x, o)); m.y = fmaxf(m.y, __shfl_xor(m.y, o));
        m.z = fmaxf(m.z, __shfl_xor(m.z, o)); m.w = fmaxf(m.w, __shfl_xor(m.w, o));
    }
    float4 ss = make_float4(0.f, 0.f, 0.f, 0.f);
    for (int i = beg + l; i < end; i += 64) {
        float4 a = alpha4[i];
        a.x = __expf(a.x - m.x); a.y = __expf(a.y - m.y);
        a.z = __expf(a.z - m.z); a.w = __expf(a.w - m.w);
        alpha4[i] = a;
        ss.x += a.x; ss.y += a.y; ss.z += a.z; ss.w += a.w;
    }
#pragma unroll
    for (int o = 32; o > 0; o >>= 1) {
        ss.x += __shfl_xor(ss.x, o); ss.y += __shfl_xor(ss.y, o);
        ss.z += __shfl_xor(ss.z, o); ss.w += __shfl_xor(ss.w, o);
    }
    if (l == 0) denomv[n] = ss;
}

// ---------------- kernel 9: aggregation + denom + bias (bf16 gathers) -----
#define AGG_CHUNK 64
__global__ __launch_bounds__(256) void k_agg(const int* __restrict__ offs,
        const int* __restrict__ csr_src, const float* __restrict__ alpha,
        const ushort* __restrict__ hb, const float4* __restrict__ denomv,
        const float* __restrict__ bias, float* __restrict__ out) {
    __shared__ int s_src[AGG_CHUNK];
    __shared__ float s_alpha[AGG_CHUNK * 4];
    int n = blockIdx.x, t = threadIdx.x;
    int beg = offs[n], end = offs[n + 1];
    int hd = t >> 6;                    // head of channels 2t, 2t+1
    float2 acc = make_float2(0.f, 0.f);
    for (int base = beg; base < end; base += AGG_CHUNK) {
        int cnt = min(AGG_CHUNK, end - base);
        __syncthreads();
        if (t < cnt) s_src[t] = csr_src[base + t];
        if (t < cnt * 4) s_alpha[t] = alpha[base * 4 + t];
        __syncthreads();
        for (int i = 0; i < cnt; i++) {
            const uint* hr = (const uint*)(hb + s_src[i] * NF);
            uint v = hr[t];
            float a = s_alpha[i * 4 + hd];
            acc.x += a * __uint_as_float(v << 16);
            acc.y += a * __uint_as_float(v & 0xFFFF0000u);
        }
    }
    float4 dn = denomv[n];
    float inv = 1.f / (((const float*)&dn)[hd] + 1e-16f);
    float o0 = acc.x * inv + bias[2 * t];
    float o1 = acc.y * inv + bias[2 * t + 1];
    *(float2*)&out[n * NF + 2 * t] = make_float2(o0, o1);
}

// ---------------- kernel 10: BN stats (block-local reduce, few atomics) ---
__global__ void k_bnstats(const float* __restrict__ x, float* __restrict__ stats) {
    int t = threadIdx.x;
    int r0 = blockIdx.x * 128;
    float s = 0.f, s2 = 0.f;
    for (int r = r0; r < r0 + 128; r++) {
        float v = x[r * NF + t];
        s += v; s2 += v * v;
    }
    atomicAdd(&stats[t], s);
    atomicAdd(&stats[NF + t], s2);
}

// ---------------- kernel 11a: BN apply + relu -> fp32 ---------------------
__global__ void k_bnapply_f32(const float* __restrict__ x, const float* __restrict__ stats,
                              const float* __restrict__ g, const float* __restrict__ b,
                              float* __restrict__ y) {
    int idx = blockIdx.x * 256 + threadIdx.x;
    int j = idx & 511;
    const float invn = 1.0f / (float)NN;
    float mu = stats[j] * invn;
    float var = stats[NF + j] * invn - mu * mu;
    float v = (x[idx] - mu) * rsqrtf(var + 1e-5f) * g[j] + b[j];
    y[idx] = fmaxf(v, 0.f);
}

// ---------------- kernel 11b: BN apply + relu -> bf16 ---------------------
__global__ void k_bnapply_bf16(const float* __restrict__ x, const float* __restrict__ stats,
                               const float* __restrict__ g, const float* __restrict__ b,
                               ushort* __restrict__ y) {
    int idx = blockIdx.x * 256 + threadIdx.x;
    int j = idx & 511;
    const float invn = 1.0f / (float)NN;
    float mu = stats[j] * invn;
    float var = stats[NF + j] * invn - mu * mu;
    float v = (x[idx] - mu) * rsqrtf(var + 1e-5f) * g[j] + b[j];
    y[idx] = f2bf(fmaxf(v, 0.f));
}

// ---------------- kernel 12: GEMM2 via bf16 MFMA --------------------------
// C[2560,512] = A[2560,512] @ B[512,512];  A bf16 row-major, BT bf16 [n][k]
// writes f32 C (for node_att) + bf16 copy (for agg gathers)
__global__ __launch_bounds__(256) void k_gemm2_mfma(const ushort* __restrict__ A,
        const ushort* __restrict__ BT, float* __restrict__ C, ushort* __restrict__ Cb) {
    __shared__ ushort As[128][40];   // [m][k], +8 pad
    __shared__ ushort Bs[128][40];   // [n][k], +8 pad
    int t = threadIdx.x;
    int rowBase = blockIdx.y * 128, colBase = blockIdx.x * 128;
    int w = t >> 6, lane = t & 63;
    int wm = (w >> 1) * 64, wn = (w & 1) * 64;
    int lm = lane & 15, q = lane >> 4;
    f32x4 acc[4][4] = {};
    int sr = t >> 2, sk = (t & 3) * 8;
    for (int k0 = 0; k0 < 512; k0 += 32) {
        __syncthreads();
        uint4 a0 = *(const uint4*)&A[(rowBase + sr) * 512 + k0 + sk];
        uint4 a1 = *(const uint4*)&A[(rowBase + 64 + sr) * 512 + k0 + sk];
        uint4 b0 = *(const uint4*)&BT[(colBase + sr) * 512 + k0 + sk];
        uint4 b1 = *(const uint4*)&BT[(colBase + 64 + sr) * 512 + k0 + sk];
        *(uint4*)&As[sr][sk]      = a0;
        *(uint4*)&As[64 + sr][sk] = a1;
        *(uint4*)&Bs[sr][sk]      = b0;
        *(uint4*)&Bs[64 + sr][sk] = b1;
        __syncthreads();
        bf16x8 af[4], bf[4];
#pragma unroll
        for (int i = 0; i < 4; i++) af[i] = *(const bf16x8*)&As[wm + i * 16 + lm][q * 8];
#pragma unroll
        for (int j = 0; j < 4; j++) bf[j] = *(const bf16x8*)&Bs[wn + j * 16 + lm][q * 8];
#pragma unroll
        for (int i = 0; i < 4; i++)
#pragma unroll
            for (int j = 0; j < 4; j++)
                acc[i][j] = __builtin_amdgcn_mfma_f32_16x16x32_bf16(af[i], bf[j], acc[i][j], 0, 0, 0);
    }
#pragma unroll
    for (int i = 0; i < 4; i++) {
        int row = rowBase + wm + i * 16 + q * 4;
#pragma unroll
        for (int j = 0; j < 4; j++) {
            int col = colBase + wn + j * 16 + lm;
#pragma unroll
            for (int r = 0; r < 4; r++) {
                float v = acc[i][j][r];
                C[(row + r) * 512 + col] = v;
                Cb[(row + r) * 512 + col] = f2bf(v);
            }
        }
    }
}

// ---------------- kernel 13: FC + mask + adjacency (LDS-staged) -----------
__global__ __launch_bounds__(256) void k_fc(const float* __restrict__ e2,
        const float* __restrict__ Wfc, const float* __restrict__ bfc,
        const int* __restrict__ mask, const float* __restrict__ adj,
        float* __restrict__ out) {
    __shared__ float er[8][512];
    int nb = blockIdx.x * 8, t = threadIdx.x;
#pragma unroll
    for (int i = 0; i < 4; i++) {
        int idx = t + i * 256;                       // float4 chunk id, 0..1023
        float4 v = *(const float4*)&e2[(nb + (idx >> 7)) * 512 + (idx & 127) * 4];
        *(float4*)&er[idx >> 7][(idx & 127) * 4] = v;
    }
    __syncthreads();
    for (int p = t; p < 8 * OUTE; p += 256) {
        int node = p / OUTE, j = p - node * OUTE;
        float acc = 0.f;
#pragma unroll 4
        for (int k = 0; k < 512; k++) acc += er[node][k] * Wfc[k * OUTE + j];
        int n = nb + node;
        float r = mask[n] ? (acc + bfc[j]) : 0.f;
        out[n * OUTE + j] = r + adj[n * OUTE + j];
    }
}

// ---------------- host side ----------------------------------------------
extern "C" void kernel_launch(void* const* d_in, const int* in_sizes, int n_in,
                              void* d_out, int out_size, void* d_ws, size_t ws_size,
                              hipStream_t stream) {
    const float* x       = (const float*)d_in[0];
    const int*   ei      = (const int*)d_in[1];
    const float* pos     = (const float*)d_in[2];
    const int*   mask    = (const int*)d_in[3];
    const float* adj     = (const float*)d_in[4];
    const float* W1      = (const float*)d_in[5];
    const float* atts1   = (const float*)d_in[6];
    const float* attd1   = (const float*)d_in[7];
    const float* We1     = (const float*)d_in[8];
    const float* atte1   = (const float*)d_in[9];
    const float* bias1   = (const float*)d_in[10];
    const float* g1      = (const float*)d_in[11];
    const float* be1     = (const float*)d_in[12];
    const float* W2      = (const float*)d_in[13];
    const float* atts2   = (const float*)d_in[14];
    const float* attd2   = (const float*)d_in[15];
    const float* We2     = (const float*)d_in[16];
    const float* atte2   = (const float*)d_in[17];
    const float* bias2   = (const float*)d_in[18];
    const float* g2      = (const float*)d_in[19];
    const float* be2     = (const float*)d_in[20];
    const float* Wfc     = (const float*)d_in[21];
    const float* bfc     = (const float*)d_in[22];
    float* out = (float*)d_out;

    // workspace layout (float-element offsets; every block 16B-aligned)
    char* ws = (char*)d_ws;
    int*    deg     = (int*)(ws);                       // 2560
    int*    cursor  = (int*)(ws + 2560 * 4);            // 2560
    float*  stats   = (float*)(ws + 5120 * 4);          // 2048 (layer1:1024, layer2:1024)
    // ---- zero region = first 7168 elements ----
    int*    offs    = (int*)(ws + 7168 * 4);            // 2561 (pad to 2576)
    float*  dote    = (float*)(ws + 9744 * 4);          // 8 (pad 16)
    float*  denomv  = (float*)(ws + 9760 * 4);          // 10240 (float4[2560])
    int*    csr_src = (int*)(ws + 20000 * 4);           // 163840
    float*  ew_csr  = (float*)(ws + 183840 * 4);        // 163840
    float*  as_     = (float*)(ws + 347680 * 4);        // 10240
    float*  ad_     = (float*)(ws + 357920 * 4);        // 10240
    float*  alpha   = (float*)(ws + 368160 * 4);        // 655360 (CSR-ordered, E*4)
    float*  t0      = (float*)(ws + 1023520 * 4);       // 1310720
    float*  t1      = (float*)(ws + 2334240 * 4);       // 1310720
    ushort* t0b     = (ushort*)(ws + 3644960 * 4);      // 1310720 bf16 (BN1 out, GEMM2 A)
    ushort* hb      = (ushort*)(ws + 4300320 * 4);      // 1310720 bf16 (h copy for agg, reused)
    ushort* W2T     = (ushort*)(ws + 4955680 * 4);      // 262144 bf16
    // total ~5.09M floats = ~20.3 MB

    hipMemsetAsync(d_ws, 0, 7168 * 4, stream);

    // graph structure + weight prep
    k_degcount<<<NE / 256, 256, 0, stream>>>(ei, deg);
    k_scan<<<1, 256, 0, stream>>>(deg, offs);
    k_csr_fill<<<NE / 256, 256, 0, stream>>>(ei, pos, offs, cursor, csr_src, ew_csr);
    k_dote2<<<2, 256, 0, stream>>>(We1, atte1, We2, atte2, dote);
    k_w2t<<<dim3(8, 8), 256, 0, stream>>>(W2, W2T);

    // ---- layer 1 ----
    k_gemm1<<<NN * NF / 256, 256, 0, stream>>>(x, W1, t0, hb);
    k_node_att<<<NN, 256, 0, stream>>>(t0, atts1, attd1, as_, ad_);
    k_softmax2<<<NN, 64, 0, stream>>>(offs, csr_src, ew_csr, (const float4*)as_,
                                      (const float4*)ad_, dote, (float4*)alpha, (float4*)denomv);
    k_agg<<<NN, 256, 0, stream>>>(offs, csr_src, alpha, hb, (const float4*)denomv, bias1, t1);
    k_bnstats<<<NN / 128, 512, 0, stream>>>(t1, stats);
    k_bnapply_bf16<<<NN * NF / 256, 256, 0, stream>>>(t1, stats, g1, be1, t0b);

    // ---- layer 2 ----
    k_gemm2_mfma<<<dim3(512 / 128, NN / 128), 256, 0, stream>>>(t0b, W2T, t0, hb);
    k_node_att<<<NN, 256, 0, stream>>>(t0, atts2, attd2, as_, ad_);
    k_softmax2<<<NN, 64, 0, stream>>>(offs, csr_src, ew_csr, (const float4*)as_,
                                      (const float4*)ad_, dote + 4, (float4*)alpha, (float4*)denomv);
    k_agg<<<NN, 256, 0, stream>>>(offs, csr_src, alpha, hb, (const float4*)denomv, bias2, t1);
    k_bnstats<<<NN / 128, 512, 0, stream>>>(t1, stats + 1024);
    k_bnapply_f32<<<NN * NF / 256, 256, 0, stream>>>(t1, stats + 1024, g2, be2, t0);

    // ---- head ----
    k_fc<<<NN / 8, 256, 0, stream>>>(t0, Wfc, bfc, mask, adj, out);
}

// Round 4
// 261.221 us; speedup vs baseline: 2.0767x; 1.2035x over previous
//
#include <hip/hip_runtime.h>
#include <hip/hip_bf16.h>

#define NN 2560        // nodes
#define NE 163840      // edges
#define NH 4           // heads
#define NC 128         // channels per head
#define NF 512         // NH*NC
#define OUTE 40

typedef short bf16x8 __attribute__((ext_vector_type(8)));
typedef float f32x4 __attribute__((ext_vector_type(4)));

__device__ inline ushort f2bf(float f) {
    uint u = __float_as_uint(f);
    uint r = u + 0x7FFF + ((u >> 16) & 1);   // round-to-nearest-even
    return (ushort)(r >> 16);
}

// ---------------- kernel 1: fused prep (degree count / dote / WfcT) ------
// blocks 0..639: degree count; 640..641: per-head edge-att scalars;
// 642..737: Wfc -> bf16 transpose [48][512] (rows 40..47 zero)
__global__ void k_prep(const int* __restrict__ ei, int* __restrict__ deg,
                       const float* __restrict__ We1, const float* __restrict__ ae1,
                       const float* __restrict__ We2, const float* __restrict__ ae2,
                       float* __restrict__ dote,
                       const float* __restrict__ Wfc, ushort* __restrict__ WfcT) {
    int b = blockIdx.x;
    if (b < 640) {
        int e = b * 256 + threadIdx.x;
        atomicAdd(&deg[ei[NE + e]], 1);
    } else if (b < 642) {
        int t = threadIdx.x;
        const float* W = (b == 641) ? We2 : We1;
        const float* A = (b == 641) ? ae2 : ae1;
        int w = t >> 6, l = t & 63;
        float p = W[w * 128 + l] * A[w * 128 + l] + W[w * 128 + 64 + l] * A[w * 128 + 64 + l];
#pragma unroll
        for (int o = 32; o > 0; o >>= 1) p += __shfl_down(p, o);
        if (l == 0) dote[(b - 640) * 4 + w] = p;
    } else {
        int idx = (b - 642) * 256 + threadIdx.x;    // j*512 + k
        int j = idx >> 9, k = idx & 511;
        WfcT[idx] = (j < OUTE) ? f2bf(Wfc[k * OUTE + j]) : (ushort)0;
    }
}

// ---------------- kernel 2: exclusive scan of deg -> offs (single block) ---
__global__ void k_scan(const int* __restrict__ deg, int* __restrict__ offs) {
    __shared__ int cs[256];
    int t = threadIdx.x;
    int base = t * 10;
    int local[10];
    int s = 0;
#pragma unroll
    for (int i = 0; i < 10; i++) { local[i] = deg[base + i]; s += local[i]; }
    cs[t] = s;
    __syncthreads();
    for (int off = 1; off < 256; off <<= 1) {
        int v = (t >= off) ? cs[t - off] : 0;
        __syncthreads();
        cs[t] += v;
        __syncthreads();
    }
    int excl = (t == 0) ? 0 : cs[t - 1];
#pragma unroll
    for (int i = 0; i < 10; i++) { offs[base + i] = excl; excl += local[i]; }
    if (t == 255) offs[NN] = excl;
}

// ---------------- kernel 3: CSR fill (src id + edge weight, CSR order) ----
__global__ void k_csr_fill(const int* __restrict__ ei, const float* __restrict__ pos,
                           const int* __restrict__ offs, int* __restrict__ cursor,
                           int* __restrict__ csr_src, float* __restrict__ ew_csr) {
    int e = blockIdx.x * 256 + threadIdx.x;
    if (e >= NE) return;
    int s = ei[e], d = ei[NE + e];
    float dx = pos[2 * s] - pos[2 * d];
    float dy = pos[2 * s + 1] - pos[2 * d + 1];
    float w = 1.0f / (sqrtf(dx * dx + dy * dy) + 1e-6f);
    int p = atomicAdd(&cursor[d], 1);
    int q = offs[d] + p;
    csr_src[q] = s;
    ew_csr[q] = w;
}

// ---------------- kernel 4: W2 transpose + bf16 cast: BT[n][k] ------------
__global__ __launch_bounds__(256) void k_w2t(const float* __restrict__ W2,
                                             ushort* __restrict__ BT) {
    __shared__ ushort tile[64][72];
    int k0 = blockIdx.y * 64, n0 = blockIdx.x * 64;
    int t = threadIdx.x;
    int r = t >> 2, cseg = (t & 3) * 16;
#pragma unroll
    for (int c = 0; c < 16; c += 4) {
        float4 v = *(const float4*)&W2[(k0 + r) * 512 + n0 + cseg + c];
        tile[cseg + c + 0][r] = f2bf(v.x);
        tile[cseg + c + 1][r] = f2bf(v.y);
        tile[cseg + c + 2][r] = f2bf(v.z);
        tile[cseg + c + 3][r] = f2bf(v.w);
    }
    __syncthreads();
    *(uint4*)&BT[(n0 + r) * 512 + k0 + cseg]     = *(uint4*)&tile[r][cseg];
    *(uint4*)&BT[(n0 + r) * 512 + k0 + cseg + 8] = *(uint4*)&tile[r][cseg + 8];
}

// ---------------- kernel 5: GEMM1 h = x @ W1 (K=32), f32 + bf16 out -------
__global__ void k_gemm1(const float* __restrict__ x, const float* __restrict__ W1,
                        float* __restrict__ h, ushort* __restrict__ hb) {
    int idx = blockIdx.x * 256 + threadIdx.x;   // n*512 + j
    int n = idx >> 9, j = idx & 511;
    const float* xr = x + n * 32;
    float acc = 0.f;
#pragma unroll
    for (int k = 0; k < 32; k++) acc += xr[k] * W1[k * 512 + j];
    h[idx] = acc;
    hb[idx] = f2bf(acc);
}

// ---------------- kernel 6: node attention scalars a_s, a_d ---------------
// one block per node, 4 waves = 4 heads
__global__ void k_node_att(const float* __restrict__ h, const float* __restrict__ atts,
                           const float* __restrict__ attd, float* __restrict__ as_,
                           float* __restrict__ ad_) {
    int n = blockIdx.x;
    int t = threadIdx.x;
    int hd = t >> 6, l = t & 63;
    const float* hr = h + n * NF + hd * NC;
    const float* sp = atts + hd * NC;
    const float* dp = attd + hd * NC;
    float ps = hr[l] * sp[l] + hr[l + 64] * sp[l + 64];
    float pd = hr[l] * dp[l] + hr[l + 64] * dp[l + 64];
#pragma unroll
    for (int o = 32; o > 0; o >>= 1) { ps += __shfl_down(ps, o); pd += __shfl_down(pd, o); }
    if (l == 0) { as_[n * 4 + hd] = ps; ad_[n * 4 + hd] = pd; }
}

// ---------------- kernel 7: fused logits + segment softmax ---------------
// one wave per dst node; alpha stored CSR-ordered: alpha4[i] for CSR pos i
__global__ void k_softmax2(const int* __restrict__ offs, const int* __restrict__ csr_src,
                           const float* __restrict__ ew_csr,
                           const float4* __restrict__ as4, const float4* __restrict__ ad4,
                           const float* __restrict__ dote, float4* __restrict__ alpha4,
                           float4* __restrict__ denomv) {
    int n = blockIdx.x, l = threadIdx.x;
    int beg = offs[n], end = offs[n + 1];
    float4 ad = ad4[n];
    float d0 = dote[0], d1 = dote[1], d2 = dote[2], d3 = dote[3];
    float4 m = make_float4(-1e30f, -1e30f, -1e30f, -1e30f);
    for (int i = beg + l; i < end; i += 64) {
        float w = ew_csr[i];
        float4 a = as4[csr_src[i]];
        float v;
        v = a.x + ad.x + w * d0; a.x = v > 0.f ? v : 0.2f * v;
        v = a.y + ad.y + w * d1; a.y = v > 0.f ? v : 0.2f * v;
        v = a.z + ad.z + w * d2; a.z = v > 0.f ? v : 0.2f * v;
        v = a.w + ad.w + w * d3; a.w = v > 0.f ? v : 0.2f * v;
        alpha4[i] = a;
        m.x = fmaxf(m.x, a.x); m.y = fmaxf(m.y, a.y);
        m.z = fmaxf(m.z, a.z); m.w = fmaxf(m.w, a.w);
    }
#pragma unroll
    for (int o = 32; o > 0; o >>= 1) {
        m.x = fmaxf(m.x, __shfl_xor(m.x, o)); m.y = fmaxf(m.y, __shfl_xor(m.y, o));
        m.z = fmaxf(m.z, __shfl_xor(m.z, o)); m.w = fmaxf(m.w, __shfl_xor(m.w, o));
    }
    float4 ss = make_float4(0.f, 0.f, 0.f, 0.f);
    for (int i = beg + l; i < end; i += 64) {
        float4 a = alpha4[i];
        a.x = __expf(a.x - m.x); a.y = __expf(a.y - m.y);
        a.z = __expf(a.z - m.z); a.w = __expf(a.w - m.w);
        alpha4[i] = a;
        ss.x += a.x; ss.y += a.y; ss.z += a.z; ss.w += a.w;
    }
#pragma unroll
    for (int o = 32; o > 0; o >>= 1) {
        ss.x += __shfl_xor(ss.x, o); ss.y += __shfl_xor(ss.y, o);
        ss.z += __shfl_xor(ss.z, o); ss.w += __shfl_xor(ss.w, o);
    }
    if (l == 0) denomv[n] = ss;
}

// ---------------- kernel 8: aggregation + denom + bias (bf16 gathers) -----
#define AGG_CHUNK 64
__global__ __launch_bounds__(256) void k_agg(const int* __restrict__ offs,
        const int* __restrict__ csr_src, const float* __restrict__ alpha,
        const ushort* __restrict__ hb, const float4* __restrict__ denomv,
        const float* __restrict__ bias, float* __restrict__ out) {
    __shared__ int s_src[AGG_CHUNK];
    __shared__ float s_alpha[AGG_CHUNK * 4];
    int n = blockIdx.x, t = threadIdx.x;
    int beg = offs[n], end = offs[n + 1];
    int hd = t >> 6;                    // head of channels 2t, 2t+1
    float2 acc = make_float2(0.f, 0.f);
    for (int base = beg; base < end; base += AGG_CHUNK) {
        int cnt = min(AGG_CHUNK, end - base);
        __syncthreads();
        if (t < cnt) s_src[t] = csr_src[base + t];
        if (t < cnt * 4) s_alpha[t] = alpha[base * 4 + t];
        __syncthreads();
        for (int i = 0; i < cnt; i++) {
            const uint* hr = (const uint*)(hb + s_src[i] * NF);
            uint v = hr[t];
            float a = s_alpha[i * 4 + hd];
            acc.x += a * __uint_as_float(v << 16);
            acc.y += a * __uint_as_float(v & 0xFFFF0000u);
        }
    }
    float4 dn = denomv[n];
    float inv = 1.f / (((const float*)&dn)[hd] + 1e-16f);
    float o0 = acc.x * inv + bias[2 * t];
    float o1 = acc.y * inv + bias[2 * t + 1];
    *(float2*)&out[n * NF + 2 * t] = make_float2(o0, o1);
}

// ---------------- kernel 9: BN stats (block-local reduce, few atomics) ----
__global__ void k_bnstats(const float* __restrict__ x, float* __restrict__ stats) {
    int t = threadIdx.x;
    int r0 = blockIdx.x * 128;
    float s = 0.f, s2 = 0.f;
    for (int r = r0; r < r0 + 128; r++) {
        float v = x[r * NF + t];
        s += v; s2 += v * v;
    }
    atomicAdd(&stats[t], s);
    atomicAdd(&stats[NF + t], s2);
}

// ---------------- kernel 10: BN apply + relu -> bf16 ----------------------
__global__ void k_bnapply_bf16(const float* __restrict__ x, const float* __restrict__ stats,
                               const float* __restrict__ g, const float* __restrict__ b,
                               ushort* __restrict__ y) {
    int idx = blockIdx.x * 256 + threadIdx.x;
    int j = idx & 511;
    const float invn = 1.0f / (float)NN;
    float mu = stats[j] * invn;
    float var = stats[NF + j] * invn - mu * mu;
    float v = (x[idx] - mu) * rsqrtf(var + 1e-5f) * g[j] + b[j];
    y[idx] = f2bf(fmaxf(v, 0.f));
}

// ---------------- kernel 11: GEMM2 via bf16 MFMA --------------------------
// C[2560,512] = A[2560,512] @ B[512,512];  A bf16 row-major, BT bf16 [n][k]
// writes f32 C (for node_att) + bf16 copy (for agg gathers)
__global__ __launch_bounds__(256) void k_gemm2_mfma(const ushort* __restrict__ A,
        const ushort* __restrict__ BT, float* __restrict__ C, ushort* __restrict__ Cb) {
    __shared__ ushort As[128][40];   // [m][k], +8 pad
    __shared__ ushort Bs[128][40];   // [n][k], +8 pad
    int t = threadIdx.x;
    int rowBase = blockIdx.y * 128, colBase = blockIdx.x * 128;
    int w = t >> 6, lane = t & 63;
    int wm = (w >> 1) * 64, wn = (w & 1) * 64;
    int lm = lane & 15, q = lane >> 4;
    f32x4 acc[4][4] = {};
    int sr = t >> 2, sk = (t & 3) * 8;
    for (int k0 = 0; k0 < 512; k0 += 32) {
        __syncthreads();
        uint4 a0 = *(const uint4*)&A[(rowBase + sr) * 512 + k0 + sk];
        uint4 a1 = *(const uint4*)&A[(rowBase + 64 + sr) * 512 + k0 + sk];
        uint4 b0 = *(const uint4*)&BT[(colBase + sr) * 512 + k0 + sk];
        uint4 b1 = *(const uint4*)&BT[(colBase + 64 + sr) * 512 + k0 + sk];
        *(uint4*)&As[sr][sk]      = a0;
        *(uint4*)&As[64 + sr][sk] = a1;
        *(uint4*)&Bs[sr][sk]      = b0;
        *(uint4*)&Bs[64 + sr][sk] = b1;
        __syncthreads();
        bf16x8 af[4], bf[4];
#pragma unroll
        for (int i = 0; i < 4; i++) af[i] = *(const bf16x8*)&As[wm + i * 16 + lm][q * 8];
#pragma unroll
        for (int j = 0; j < 4; j++) bf[j] = *(const bf16x8*)&Bs[wn + j * 16 + lm][q * 8];
#pragma unroll
        for (int i = 0; i < 4; i++)
#pragma unroll
            for (int j = 0; j < 4; j++)
                acc[i][j] = __builtin_amdgcn_mfma_f32_16x16x32_bf16(af[i], bf[j], acc[i][j], 0, 0, 0);
    }
#pragma unroll
    for (int i = 0; i < 4; i++) {
        int row = rowBase + wm + i * 16 + q * 4;
#pragma unroll
        for (int j = 0; j < 4; j++) {
            int col = colBase + wn + j * 16 + lm;
#pragma unroll
            for (int r = 0; r < 4; r++) {
                float v = acc[i][j][r];
                C[(row + r) * 512 + col] = v;
                Cb[(row + r) * 512 + col] = f2bf(v);
            }
        }
    }
}

// ---------------- kernel 12: FC via MFMA + mask + adjacency ---------------
// out[2560,40] = e2b[2560,512] @ WfcT^T ; one wave per 16 rows, N=48 (3 tiles)
__global__ __launch_bounds__(64) void k_fc_mfma(const ushort* __restrict__ e2b,
        const ushort* __restrict__ WfcT, const float* __restrict__ bfc,
        const int* __restrict__ mask, const float* __restrict__ adj,
        float* __restrict__ out) {
    int lane = threadIdx.x;
    int r0 = blockIdx.x * 16;
    int lm = lane & 15, q = lane >> 4;
    f32x4 acc[3] = {};
#pragma unroll
    for (int k0 = 0; k0 < 512; k0 += 32) {
        bf16x8 af = *(const bf16x8*)&e2b[(r0 + lm) * 512 + k0 + q * 8];
#pragma unroll
        for (int jt = 0; jt < 3; jt++) {
            bf16x8 bf = *(const bf16x8*)&WfcT[(jt * 16 + lm) * 512 + k0 + q * 8];
            acc[jt] = __builtin_amdgcn_mfma_f32_16x16x32_bf16(af, bf, acc[jt], 0, 0, 0);
        }
    }
#pragma unroll
    for (int jt = 0; jt < 3; jt++) {
        int col = jt * 16 + lm;
        if (col < OUTE) {
#pragma unroll
            for (int r = 0; r < 4; r++) {
                int n = r0 + q * 4 + r;
                float v = acc[jt][r] + bfc[col];
                v = mask[n] ? v : 0.f;
                out[n * OUTE + col] = v + adj[n * OUTE + col];
            }
        }
    }
}

// ---------------- host side ----------------------------------------------
extern "C" void kernel_launch(void* const* d_in, const int* in_sizes, int n_in,
                              void* d_out, int out_size, void* d_ws, size_t ws_size,
                              hipStream_t stream) {
    const float* x       = (const float*)d_in[0];
    const int*   ei      = (const int*)d_in[1];
    const float* pos     = (const float*)d_in[2];
    const int*   mask    = (const int*)d_in[3];
    const float* adj     = (const float*)d_in[4];
    const float* W1      = (const float*)d_in[5];
    const float* atts1   = (const float*)d_in[6];
    const float* attd1   = (const float*)d_in[7];
    const float* We1     = (const float*)d_in[8];
    const float* atte1   = (const float*)d_in[9];
    const float* bias1   = (const float*)d_in[10];
    const float* g1      = (const float*)d_in[11];
    const float* be1     = (const float*)d_in[12];
    const float* W2      = (const float*)d_in[13];
    const float* atts2   = (const float*)d_in[14];
    const float* attd2   = (const float*)d_in[15];
    const float* We2     = (const float*)d_in[16];
    const float* atte2   = (const float*)d_in[17];
    const float* bias2   = (const float*)d_in[18];
    const float* g2      = (const float*)d_in[19];
    const float* be2     = (const float*)d_in[20];
    const float* Wfc     = (const float*)d_in[21];
    const float* bfc     = (const float*)d_in[22];
    float* out = (float*)d_out;

    // workspace layout (float-element offsets; every block 16B-aligned)
    char* ws = (char*)d_ws;
    int*    deg     = (int*)(ws);                       // 2560
    int*    cursor  = (int*)(ws + 2560 * 4);            // 2560
    float*  stats   = (float*)(ws + 5120 * 4);          // 2048 (layer1:1024, layer2:1024)
    // ---- zero region = first 7168 elements ----
    int*    offs    = (int*)(ws + 7168 * 4);            // 2561 (pad to 2576)
    float*  dote    = (float*)(ws + 9744 * 4);          // 8 (pad 16)
    float*  denomv  = (float*)(ws + 9760 * 4);          // 10240 (float4[2560])
    int*    csr_src = (int*)(ws + 20000 * 4);           // 163840
    float*  ew_csr  = (float*)(ws + 183840 * 4);        // 163840
    float*  as_     = (float*)(ws + 347680 * 4);        // 10240
    float*  ad_     = (float*)(ws + 357920 * 4);        // 10240
    float*  alpha   = (float*)(ws + 368160 * 4);        // 655360 (CSR-ordered, E*4)
    float*  t0      = (float*)(ws + 1023520 * 4);       // 1310720
    float*  t1      = (float*)(ws + 2334240 * 4);       // 1310720
    ushort* t0b     = (ushort*)(ws + 3644960 * 4);      // 1310720 bf16 (BN1 out / BN2 out)
    ushort* hb      = (ushort*)(ws + 4300320 * 4);      // 1310720 bf16 (h copy for agg)
    ushort* W2T     = (ushort*)(ws + 4955680 * 4);      // 262144 bf16
    ushort* WfcT    = (ushort*)(ws + 5086752 * 4);      // 24576 bf16 [48][512]
    // total ~5.10M floats = ~20.4 MB

    hipMemsetAsync(d_ws, 0, 7168 * 4, stream);

    // graph structure + weight prep
    k_prep<<<738, 256, 0, stream>>>(ei, deg, We1, atte1, We2, atte2, dote, Wfc, WfcT);
    k_scan<<<1, 256, 0, stream>>>(deg, offs);
    k_csr_fill<<<NE / 256, 256, 0, stream>>>(ei, pos, offs, cursor, csr_src, ew_csr);
    k_w2t<<<dim3(8, 8), 256, 0, stream>>>(W2, W2T);

    // ---- layer 1 ----
    k_gemm1<<<NN * NF / 256, 256, 0, stream>>>(x, W1, t0, hb);
    k_node_att<<<NN, 256, 0, stream>>>(t0, atts1, attd1, as_, ad_);
    k_softmax2<<<NN, 64, 0, stream>>>(offs, csr_src, ew_csr, (const float4*)as_,
                                      (const float4*)ad_, dote, (float4*)alpha, (float4*)denomv);
    k_agg<<<NN, 256, 0, stream>>>(offs, csr_src, alpha, hb, (const float4*)denomv, bias1, t1);
    k_bnstats<<<NN / 128, 512, 0, stream>>>(t1, stats);
    k_bnapply_bf16<<<NN * NF / 256, 256, 0, stream>>>(t1, stats, g1, be1, t0b);

    // ---- layer 2 ----
    k_gemm2_mfma<<<dim3(512 / 128, NN / 128), 256, 0, stream>>>(t0b, W2T, t0, hb);
    k_node_att<<<NN, 256, 0, stream>>>(t0, atts2, attd2, as_, ad_);
    k_softmax2<<<NN, 64, 0, stream>>>(offs, csr_src, ew_csr, (const float4*)as_,
                                      (const float4*)ad_, dote + 4, (float4*)alpha, (float4*)denomv);
    k_agg<<<NN, 256, 0, stream>>>(offs, csr_src, alpha, hb, (const float4*)denomv, bias2, t1);
    k_bnstats<<<NN / 128, 512, 0, stream>>>(t1, stats + 1024);
    k_bnapply_bf16<<<NN * NF / 256, 256, 0, stream>>>(t1, stats + 1024, g2, be2, t0b);

    // ---- head ----
    k_fc_mfma<<<NN / 16, 64, 0, stream>>>(t0b, WfcT, bfc, mask, adj, out);
}